// Round 5
// baseline (666.673 us; speedup 1.0000x reference)
//
#include <hip/hip_runtime.h>
#include <math.h>

// SpectralAttention gfx950 — round 5: latency-hiding pipelines.
// flash: single-barrier double-buffered K/V staging; vectorized V staging.
// GEMMs: single-barrier double-buffer.
// B=2, T=2048, C=1024, H=16, HD=64.
//
// Packed split format (u32): lo16 = fp16(v) ["hi" part], hi16 = fp16((v-hi)*2048).
// v = hi + lo/2048 to ~2^-22 rel.  3-term MFMA: D = Ah*Bh + (Ah*Bl + Al*Bh)/2048.
//
// ws layout (floats) with region reuse:
//   [0,  4M)  qT -> qpk -> wopk     [4M, 8M)  kT -> kpk    [8M, 12M) vT -> vpk
//   [12M,16M) wqkv-pk -> qipk      [16M,20M) kipk
//   [20M,24M) xpk -> attpk         24M: tables
// total 96 MB + 16 KB

typedef _Float16 half8 __attribute__((ext_vector_type(8)));
typedef float f32x4 __attribute__((ext_vector_type(4)));
#define MFMA16 __builtin_amdgcn_mfma_f32_16x16x32_f16

__device__ inline unsigned pack_split(float v) {
    _Float16 h = (_Float16)v;
    float r = (v - (float)h) * 2048.0f;
    _Float16 l = (_Float16)r;
    union { _Float16 f; unsigned short u; } a, b;
    a.f = h; b.f = l;
    return (unsigned)a.u | ((unsigned)b.u << 16);
}
__device__ inline _Float16 lo16(unsigned u) {
    union { unsigned short s; _Float16 f; } x; x.s = (unsigned short)(u & 0xffffu); return x.f;
}
__device__ inline _Float16 hi16(unsigned u) {
    union { unsigned short s; _Float16 f; } x; x.s = (unsigned short)(u >> 16); return x.f;
}

// split 8 packed u32 into hi-half8 / lo-half8 via byte-perms, store as 2 b128
__device__ inline void write_split(_Float16* dh, _Float16* dl, uint4 u0, uint4 u1) {
    uint4 lo, hi;
    lo.x = __builtin_amdgcn_perm(u0.y, u0.x, 0x05040100u);
    lo.y = __builtin_amdgcn_perm(u0.w, u0.z, 0x05040100u);
    lo.z = __builtin_amdgcn_perm(u1.y, u1.x, 0x05040100u);
    lo.w = __builtin_amdgcn_perm(u1.w, u1.z, 0x05040100u);
    hi.x = __builtin_amdgcn_perm(u0.y, u0.x, 0x07060302u);
    hi.y = __builtin_amdgcn_perm(u0.w, u0.z, 0x07060302u);
    hi.z = __builtin_amdgcn_perm(u1.y, u1.x, 0x07060302u);
    hi.w = __builtin_amdgcn_perm(u1.w, u1.z, 0x07060302u);
    *(uint4*)dh = lo;
    *(uint4*)dl = hi;
}

// ---------------------------------------------------------------- init tables
__global__ __launch_bounds__(256) void k_init_tables(
    float2* __restrict__ tw, float2* __restrict__ filt,
    const float* __restrict__ fd, const float* __restrict__ alpha,
    const float* __restrict__ fas)
{
    int i = blockIdx.x * 256 + threadIdx.x;
    double aa = (double)alpha[0] + (double)fas[0] * ((double)fd[0] - 1.5);
    if (i < 1024) {
        double ang = -2.0 * 3.14159265358979323846 * (double)i / 2048.0;
        double s, c;
        sincos(ang, &s, &c);
        tw[i] = make_float2((float)c, (float)s);
    }
    if (i < 2048) {
        double fr = (i < 1024) ? (double)i / 2048.0 : ((double)i - 2048.0) / 2048.0;
        double ph = aa * atan(log(fabs(fr) + 1e-10));
        double s, c;
        sincos(ph, &s, &c);
        filt[i] = make_float2((float)c, (float)s);
    }
}

// ------------------------------------------------------- prep: W^T pack-split
__global__ __launch_bounds__(256) void k_prep_w(
    const float* __restrict__ W, unsigned* __restrict__ Wpk)
{
    __shared__ float tile[64][65];
    const int kb = blockIdx.x * 64, cb = blockIdx.y * 64;
    const int t = threadIdx.x, r = t >> 4, c4 = (t & 15) * 4;
#pragma unroll
    for (int i = 0; i < 4; ++i) {
        int row = r + 16 * i;
        float4 v = *(const float4*)&W[(size_t)(kb + row) * 1024 + cb + c4];
        tile[row][c4 + 0] = v.x; tile[row][c4 + 1] = v.y;
        tile[row][c4 + 2] = v.z; tile[row][c4 + 3] = v.w;
    }
    __syncthreads();
#pragma unroll
    for (int i = 0; i < 4; ++i) {
        int crow = r + 16 * i;
        uint4 o;
        o.x = pack_split(tile[c4 + 0][crow]);
        o.y = pack_split(tile[c4 + 1][crow]);
        o.z = pack_split(tile[c4 + 2][crow]);
        o.w = pack_split(tile[c4 + 3][crow]);
        *(uint4*)&Wpk[(size_t)(cb + crow) * 1024 + kb + c4] = o;
    }
}

// ------------------------------------------------------- prep: x pack-split
__global__ __launch_bounds__(256) void k_prep_x(
    const float* __restrict__ x, unsigned* __restrict__ xpk)
{
    const int base = blockIdx.x * 4096 + threadIdx.x * 4;
#pragma unroll
    for (int i = 0; i < 4; ++i) {
        int idx = base + i * 1024;
        float4 v = *(const float4*)&x[idx];
        uint4 o;
        o.x = pack_split(v.x); o.y = pack_split(v.y);
        o.z = pack_split(v.z); o.w = pack_split(v.w);
        *(uint4*)&xpk[idx] = o;
    }
}

// --------------------------------------------------- QKV GEMM (MFMA f16-split)
// out^T[c][t] = W^T X^T. 128x128 tile, dbuf LDS, 1 barrier/K-step.
__global__ __launch_bounds__(256) void k_gemm_qkv(
    const unsigned* __restrict__ xpk, const unsigned* __restrict__ wpk,
    const float* __restrict__ bq, const float* __restrict__ bk,
    const float* __restrict__ bv,
    float* __restrict__ qT, float* __restrict__ kT, float* __restrict__ vT)
{
    __shared__ __align__(16) _Float16 Ab[2][8][2][64][8];   // 32 KB
    __shared__ __align__(16) _Float16 Bb[2][8][2][64][8];   // 32 KB
    const int tid = threadIdx.x;
    const int mat = blockIdx.z;
    const unsigned* Apk = wpk + (size_t)mat * 1048576;
    const float* bias = (mat == 0) ? bq : (mat == 1) ? bk : bv;
    float* outp       = (mat == 0) ? qT : (mat == 1) ? kT : vT;
    const int m0 = blockIdx.x * 128, n0 = blockIdx.y * 128;
    const int w = tid >> 6, lane = tid & 63, quad = lane >> 4, l15 = lane & 15;
    const int wm = (w & 1) * 4, wn = (w >> 1) * 4;

    const int chA = tid & 3, rA = tid >> 2;
    const int flA = (rA & 15) + 16 * chA, mtA = rA >> 4;
    const unsigned* gA0 = &Apk[(size_t)(m0 + rA) * 1024 + chA * 8];
    const unsigned* gA1 = gA0 + (size_t)64 * 1024;
    const unsigned* gB0 = &xpk[(size_t)(n0 + rA) * 1024 + chA * 8];
    const unsigned* gB1 = gB0 + (size_t)64 * 1024;

    uint4 pa0 = *(const uint4*)gA0, pa1 = *(const uint4*)(gA0 + 4);
    uint4 pa2 = *(const uint4*)gA1, pa3 = *(const uint4*)(gA1 + 4);
    uint4 pb0 = *(const uint4*)gB0, pb1 = *(const uint4*)(gB0 + 4);
    uint4 pb2 = *(const uint4*)gB1, pb3 = *(const uint4*)(gB1 + 4);

    f32x4 acc1[4][4], acc2[4][4];
    const f32x4 z4 = {0.f, 0.f, 0.f, 0.f};
#pragma unroll
    for (int i = 0; i < 4; ++i)
#pragma unroll
        for (int j = 0; j < 4; ++j) { acc1[i][j] = z4; acc2[i][j] = z4; }

    // prologue: stage k0=0 into buf 0
    write_split(&Ab[0][mtA][0][flA][0],     &Ab[0][mtA][1][flA][0],     pa0, pa1);
    write_split(&Ab[0][mtA + 4][0][flA][0], &Ab[0][mtA + 4][1][flA][0], pa2, pa3);
    write_split(&Bb[0][mtA][0][flA][0],     &Bb[0][mtA][1][flA][0],     pb0, pb1);
    write_split(&Bb[0][mtA + 4][0][flA][0], &Bb[0][mtA + 4][1][flA][0], pb2, pb3);

    for (int k0 = 0; k0 < 1024; k0 += 32) {
        const int buf = (k0 >> 5) & 1;
        __syncthreads();
        if (k0 < 992) {
            int kn = k0 + 32;
            pa0 = *(const uint4*)(gA0 + kn); pa1 = *(const uint4*)(gA0 + kn + 4);
            pa2 = *(const uint4*)(gA1 + kn); pa3 = *(const uint4*)(gA1 + kn + 4);
            pb0 = *(const uint4*)(gB0 + kn); pb1 = *(const uint4*)(gB0 + kn + 4);
            pb2 = *(const uint4*)(gB1 + kn); pb3 = *(const uint4*)(gB1 + kn + 4);
        }
        half8 ah[4], al[4];
#pragma unroll
        for (int mt = 0; mt < 4; ++mt) {
            ah[mt] = *(half8*)&Ab[buf][wm + mt][0][lane][0];
            al[mt] = *(half8*)&Ab[buf][wm + mt][1][lane][0];
        }
#pragma unroll
        for (int nt = 0; nt < 4; ++nt) {
            half8 bh = *(half8*)&Bb[buf][wn + nt][0][lane][0];
            half8 bl = *(half8*)&Bb[buf][wn + nt][1][lane][0];
#pragma unroll
            for (int mt = 0; mt < 4; ++mt) {
                acc1[mt][nt] = MFMA16(ah[mt], bh, acc1[mt][nt], 0, 0, 0);
                acc2[mt][nt] = MFMA16(ah[mt], bl, acc2[mt][nt], 0, 0, 0);
                acc2[mt][nt] = MFMA16(al[mt], bh, acc2[mt][nt], 0, 0, 0);
            }
        }
        if (k0 < 992) {
            const int nb = buf ^ 1;
            write_split(&Ab[nb][mtA][0][flA][0],     &Ab[nb][mtA][1][flA][0],     pa0, pa1);
            write_split(&Ab[nb][mtA + 4][0][flA][0], &Ab[nb][mtA + 4][1][flA][0], pa2, pa3);
            write_split(&Bb[nb][mtA][0][flA][0],     &Bb[nb][mtA][1][flA][0],     pb0, pb1);
            write_split(&Bb[nb][mtA + 4][0][flA][0], &Bb[nb][mtA + 4][1][flA][0], pb2, pb3);
        }
    }
    const int b_ = n0 >> 11, t0 = n0 & 2047;
#pragma unroll
    for (int mt = 0; mt < 4; ++mt) {
#pragma unroll
        for (int r_ = 0; r_ < 4; ++r_) {
            int m = m0 + (wm + mt) * 16 + quad * 4 + r_;
            float bs = bias[m];
            float* orow = &outp[(size_t)(b_ * 1024 + m) * 2048 + t0];
#pragma unroll
            for (int nt = 0; nt < 4; ++nt) {
                float val = acc1[mt][nt][r_] + acc2[mt][nt][r_] * (1.f / 2048.f) + bs;
                orow[(wn + nt) * 16 + l15] = val;
            }
        }
    }
}

// ------------------------------------------------------------- FFT + filter
__global__ __launch_bounds__(256) void k_fft_filter(
    float* __restrict__ qT, float* __restrict__ kT, float* __restrict__ vT,
    float* __restrict__ qiT, float* __restrict__ kiT,
    const float2* __restrict__ tw, const float2* __restrict__ filt)
{
    __shared__ float2 sf[2048];
    const int bid = blockIdx.x;          // 0..6143
    const int mat = bid >> 11;
    const int seq = bid & 2047;
    float* base = (mat == 0) ? qT : (mat == 1) ? kT : vT;
    float* src = base + (size_t)seq * 2048;
    const int tid = threadIdx.x;

    for (int i = tid; i < 2048; i += 256) {
        int j = (int)(__brev((unsigned)i) >> 21);
        sf[j] = make_float2(src[i], 0.f);
    }
    __syncthreads();
    for (int st = 1; st <= 11; ++st) {
        const int half = 1 << (st - 1);
        const int shift = 11 - st;
        for (int u = tid; u < 1024; u += 256) {
            int pos = u & (half - 1);
            int bi = 2 * u - pos;
            float2 w = tw[pos << shift];
            float2 a = sf[bi], b = sf[bi + half];
            float tr = w.x * b.x - w.y * b.y;
            float ti = w.x * b.y + w.y * b.x;
            sf[bi]        = make_float2(a.x + tr, a.y + ti);
            sf[bi + half] = make_float2(a.x - tr, a.y - ti);
        }
        __syncthreads();
    }
    unsigned* dst_re = (unsigned*)src;
    unsigned* dst_im = (mat == 0) ? (unsigned*)(qiT + (size_t)seq * 2048)
                                  : (unsigned*)(kiT + (size_t)seq * 2048);
    for (int i = tid; i < 2048; i += 256) {
        float2 z = sf[i];
        float2 f = filt[i];
        float re = z.x * f.x - z.y * f.y;
        float im = z.x * f.y + z.y * f.x;
        if (mat == 0) {
            dst_re[i] = pack_split(0.125f * re);
            dst_im[i] = pack_split(0.125f * im);
        } else if (mat == 1) {
            dst_re[i] = pack_split(re);
            dst_im[i] = pack_split(-im);
        } else {
            dst_re[i] = pack_split(re);
        }
    }
}

// ------------------------------------------------------------- flash (MFMA f16)
// 512 thr = 8 waves; block = (bh, t-tile 128); s-step 32.
// Single-barrier double-buffered K/V staging; V staged in B-frag row order.
__global__ __launch_bounds__(512) void k_flash(
    const unsigned* __restrict__ qpk, const unsigned* __restrict__ qipk,
    const unsigned* __restrict__ kpk, const unsigned* __restrict__ kipk,
    const unsigned* __restrict__ vpk, unsigned* __restrict__ attpk)
{
    __shared__ __align__(16) _Float16 Kbuf[2][2][4][2][64][8];  // 32KB
    __shared__ __align__(16) _Float16 Vbuf[2][4][2][64][8];     // 16KB
    __shared__ __align__(16) _Float16 Pbuf[8][16][32];          //  8KB

    const int tid = threadIdx.x;
    const int w = tid >> 6, lane = tid & 63;
    const int quad = lane >> 4, l15 = lane & 15;
    const int bh = blockIdx.x >> 4, tb = blockIdx.x & 15;
    const size_t bc = (size_t)bh * 64;
    const int tw0 = tb * 128 + w * 16;

    // Q A-frags in registers (loaded once)
    half8 aqh[4], aql[4];
#pragma unroll
    for (int kc = 0; kc < 4; ++kc) {
#pragma unroll
        for (int j = 0; j < 8; ++j) {
            int d = kc * 32 + quad * 8 + j;
            int t = tw0 + l15;
            unsigned u = (d < 64) ? qpk[(bc + d) * 2048 + t]
                                  : qipk[(bc + d - 64) * 2048 + t];
            aqh[kc][j] = lo16(u);
            aql[kc][j] = hi16(u);
        }
    }

    f32x4 O1[4], O2[4];
    const f32x4 zero4 = {0.f, 0.f, 0.f, 0.f};
#pragma unroll
    for (int nt = 0; nt < 4; ++nt) { O1[nt] = zero4; O2[nt] = zero4; }
    float m_[4] = {-3e38f, -3e38f, -3e38f, -3e38f};
    float l_[4] = {0.f, 0.f, 0.f, 0.f};

    // K staging task (all 512): 8 d-strided u32 at s = s0 + sK
    const int sK = tid & 31, dcK = tid >> 5;
    const int stK = sK >> 4, kcK = dcK >> 2, qK = dcK & 3;
    const int laneK = (sK & 15) + qK * 16;
    // V staging task (tid<256): 8 consecutive s at fixed d, B-frag row order
    const int ntV = tid >> 6, laneV = tid & 63;
    const int dV = ntV * 16 + (laneV & 15), sV8 = (laneV >> 4) * 8;

    unsigned ku[8];
    uint4 va0, va1;

    // prologue: load + stage tile 0 into buf 0
#pragma unroll
    for (int j = 0; j < 8; ++j) {
        int d = dcK * 8 + j;
        ku[j] = (d < 64) ? kpk[(bc + d) * 2048 + sK]
                         : kipk[(bc + d - 64) * 2048 + sK];
    }
    if (tid < 256) {
        const unsigned* vp = &vpk[(bc + dV) * 2048 + sV8];
        va0 = *(const uint4*)vp; va1 = *(const uint4*)(vp + 4);
    }
    write_split(&Kbuf[0][stK][kcK][0][laneK][0], &Kbuf[0][stK][kcK][1][laneK][0],
                *(uint4*)&ku[0], *(uint4*)&ku[4]);
    if (tid < 256)
        write_split(&Vbuf[0][ntV][0][laneV][0], &Vbuf[0][ntV][1][laneV][0], va0, va1);

    for (int it = 0; it < 64; ++it) {
        const int buf = it & 1;
        __syncthreads();
        // issue next tile's global loads (overlap with compute below)
        if (it < 63) {
            const int sn = (it + 1) * 32;
#pragma unroll
            for (int j = 0; j < 8; ++j) {
                int d = dcK * 8 + j;
                ku[j] = (d < 64) ? kpk[(bc + d) * 2048 + sn + sK]
                                 : kipk[(bc + d - 64) * 2048 + sn + sK];
            }
            if (tid < 256) {
                const unsigned* vp = &vpk[(bc + dV) * 2048 + sn + sV8];
                va0 = *(const uint4*)vp; va1 = *(const uint4*)(vp + 4);
            }
        }

        // --- S = Q.K^T (3-term split)
        f32x4 S1[2], S2[2];
#pragma unroll
        for (int st = 0; st < 2; ++st) { S1[st] = zero4; S2[st] = zero4; }
#pragma unroll
        for (int st = 0; st < 2; ++st) {
#pragma unroll
            for (int kc = 0; kc < 4; ++kc) {
                half8 bhf = *(half8*)&Kbuf[buf][st][kc][0][lane][0];
                half8 blf = *(half8*)&Kbuf[buf][st][kc][1][lane][0];
                S1[st] = MFMA16(aqh[kc], bhf, S1[st], 0, 0, 0);
                S2[st] = MFMA16(aqh[kc], blf, S2[st], 0, 0, 0);
                S2[st] = MFMA16(aql[kc], bhf, S2[st], 0, 0, 0);
            }
        }

        // --- online softmax
#pragma unroll
        for (int r = 0; r < 4; ++r) {
            float v0 = S1[0][r] + S2[0][r] * (1.f / 2048.f);
            float v1 = S1[1][r] + S2[1][r] * (1.f / 2048.f);
            float mt = fmaxf(v0, v1);
#pragma unroll
            for (int msk = 1; msk < 16; msk <<= 1)
                mt = fmaxf(mt, __shfl_xor(mt, msk, 16));
            float mn = fmaxf(m_[r], mt);
            float al = __expf(m_[r] - mn);
            m_[r] = mn;
            float p0 = __expf(v0 - mn);
            float p1 = __expf(v1 - mn);
            float rs = p0 + p1;
#pragma unroll
            for (int msk = 1; msk < 16; msk <<= 1)
                rs += __shfl_xor(rs, msk, 16);
            l_[r] = l_[r] * al + rs;
#pragma unroll
            for (int nt = 0; nt < 4; ++nt) { O1[nt][r] *= al; O2[nt][r] *= al; }
            int t = quad * 4 + r;
            Pbuf[w][t][l15]      = (_Float16)p0;
            Pbuf[w][t][l15 + 16] = (_Float16)p1;
        }
        // Pbuf is wave-private: no barrier needed

        // --- PV accumulate
        half8 ap = *(half8*)&Pbuf[w][l15][quad * 8];
#pragma unroll
        for (int nt = 0; nt < 4; ++nt) {
            half8 vh = *(half8*)&Vbuf[buf][nt][0][lane][0];
            half8 vl = *(half8*)&Vbuf[buf][nt][1][lane][0];
            O1[nt] = MFMA16(ap, vh, O1[nt], 0, 0, 0);
            O2[nt] = MFMA16(ap, vl, O2[nt], 0, 0, 0);
        }

        // --- write next tile into the other buffer (no barrier needed before)
        if (it < 63) {
            const int nb = buf ^ 1;
            write_split(&Kbuf[nb][stK][kcK][0][laneK][0],
                        &Kbuf[nb][stK][kcK][1][laneK][0],
                        *(uint4*)&ku[0], *(uint4*)&ku[4]);
            if (tid < 256)
                write_split(&Vbuf[nb][ntV][0][laneV][0],
                            &Vbuf[nb][ntV][1][laneV][0], va0, va1);
        }
    }

    const int b = bh >> 4, h = bh & 15;
#pragma unroll
    for (int r = 0; r < 4; ++r) {
        float inv = 1.0f / l_[r];
        int t = tw0 + quad * 4 + r;
        size_t row = (size_t)b * 2048 + t;
#pragma unroll
        for (int nt = 0; nt < 4; ++nt) {
            float val = (O1[nt][r] + O2[nt][r] * (1.f / 2048.f)) * inv;
            attpk[row * 1024 + h * 64 + nt * 16 + l15] = pack_split(val);
        }
    }
}

// --------------------------------------------------- out GEMM (MFMA f16-split)
__global__ __launch_bounds__(256) void k_gemm_out(
    const unsigned* __restrict__ attpk, const unsigned* __restrict__ wopk,
    const float* __restrict__ bo, float* __restrict__ out)
{
    __shared__ __align__(16) _Float16 Ab[2][8][2][64][8];
    __shared__ __align__(16) _Float16 Bb[2][8][2][64][8];
    const int tid = threadIdx.x;
    const int m0 = blockIdx.x * 128, n0 = blockIdx.y * 128;
    const int w = tid >> 6, lane = tid & 63, quad = lane >> 4, l15 = lane & 15;
    const int wm = (w & 1) * 4, wn = (w >> 1) * 4;

    const int chA = tid & 3, rA = tid >> 2;
    const int flA = (rA & 15) + 16 * chA, mtA = rA >> 4;
    const unsigned* gA0 = &attpk[(size_t)(m0 + rA) * 1024 + chA * 8];
    const unsigned* gA1 = gA0 + (size_t)64 * 1024;
    const unsigned* gB0 = &wopk[(size_t)(n0 + rA) * 1024 + chA * 8];
    const unsigned* gB1 = gB0 + (size_t)64 * 1024;

    uint4 pa0 = *(const uint4*)gA0, pa1 = *(const uint4*)(gA0 + 4);
    uint4 pa2 = *(const uint4*)gA1, pa3 = *(const uint4*)(gA1 + 4);
    uint4 pb0 = *(const uint4*)gB0, pb1 = *(const uint4*)(gB0 + 4);
    uint4 pb2 = *(const uint4*)gB1, pb3 = *(const uint4*)(gB1 + 4);

    f32x4 acc1[4][4], acc2[4][4];
    const f32x4 z4 = {0.f, 0.f, 0.f, 0.f};
#pragma unroll
    for (int i = 0; i < 4; ++i)
#pragma unroll
        for (int j = 0; j < 4; ++j) { acc1[i][j] = z4; acc2[i][j] = z4; }

    write_split(&Ab[0][mtA][0][flA][0],     &Ab[0][mtA][1][flA][0],     pa0, pa1);
    write_split(&Ab[0][mtA + 4][0][flA][0], &Ab[0][mtA + 4][1][flA][0], pa2, pa3);
    write_split(&Bb[0][mtA][0][flA][0],     &Bb[0][mtA][1][flA][0],     pb0, pb1);
    write_split(&Bb[0][mtA + 4][0][flA][0], &Bb[0][mtA + 4][1][flA][0], pb2, pb3);

    for (int k0 = 0; k0 < 1024; k0 += 32) {
        const int buf = (k0 >> 5) & 1;
        __syncthreads();
        if (k0 < 992) {
            int kn = k0 + 32;
            pa0 = *(const uint4*)(gA0 + kn); pa1 = *(const uint4*)(gA0 + kn + 4);
            pa2 = *(const uint4*)(gA1 + kn); pa3 = *(const uint4*)(gA1 + kn + 4);
            pb0 = *(const uint4*)(gB0 + kn); pb1 = *(const uint4*)(gB0 + kn + 4);
            pb2 = *(const uint4*)(gB1 + kn); pb3 = *(const uint4*)(gB1 + kn + 4);
        }
        half8 ah[4], al[4];
#pragma unroll
        for (int mt = 0; mt < 4; ++mt) {
            ah[mt] = *(half8*)&Ab[buf][wm + mt][0][lane][0];
            al[mt] = *(half8*)&Ab[buf][wm + mt][1][lane][0];
        }
#pragma unroll
        for (int nt = 0; nt < 4; ++nt) {
            half8 bh = *(half8*)&Bb[buf][wn + nt][0][lane][0];
            half8 bl = *(half8*)&Bb[buf][wn + nt][1][lane][0];
#pragma unroll
            for (int mt = 0; mt < 4; ++mt) {
                acc1[mt][nt] = MFMA16(ah[mt], bh, acc1[mt][nt], 0, 0, 0);
                acc2[mt][nt] = MFMA16(ah[mt], bl, acc2[mt][nt], 0, 0, 0);
                acc2[mt][nt] = MFMA16(al[mt], bh, acc2[mt][nt], 0, 0, 0);
            }
        }
        if (k0 < 992) {
            const int nb = buf ^ 1;
            write_split(&Ab[nb][mtA][0][flA][0],     &Ab[nb][mtA][1][flA][0],     pa0, pa1);
            write_split(&Ab[nb][mtA + 4][0][flA][0], &Ab[nb][mtA + 4][1][flA][0], pa2, pa3);
            write_split(&Bb[nb][mtA][0][flA][0],     &Bb[nb][mtA][1][flA][0],     pb0, pb1);
            write_split(&Bb[nb][mtA + 4][0][flA][0], &Bb[nb][mtA + 4][1][flA][0], pb2, pb3);
        }
    }
#pragma unroll
    for (int mt = 0; mt < 4; ++mt) {
#pragma unroll
        for (int r_ = 0; r_ < 4; ++r_) {
            int m = m0 + (wm + mt) * 16 + quad * 4 + r_;
            float* orow = &out[(size_t)m * 1024 + n0];
#pragma unroll
            for (int nt = 0; nt < 4; ++nt) {
                int n = (wn + nt) * 16 + l15;
                float val = acc1[mt][nt][r_] + acc2[mt][nt][r_] * (1.f / 2048.f)
                          + bo[n0 + n];
                orow[n] = val;
            }
        }
    }
}

// ------------------------------------------------------------- energy renorm
__global__ __launch_bounds__(256) void k_norm(
    const float* __restrict__ x, float* __restrict__ out,
    const float* __restrict__ en)
{
    const int row = blockIdx.x;
    const int tid = threadIdx.x;
    const float* xr = x + (size_t)row * 1024;
    float* orow = out + (size_t)row * 1024;
    float4 xv = *(const float4*)&xr[tid * 4];
    float4 ov = *(const float4*)&orow[tid * 4];
    float ssx = xv.x * xv.x + xv.y * xv.y + xv.z * xv.z + xv.w * xv.w;
    float sso = ov.x * ov.x + ov.y * ov.y + ov.z * ov.z + ov.w * ov.w;
#pragma unroll
    for (int m = 1; m <= 32; m <<= 1) {
        ssx += __shfl_xor(ssx, m, 64);
        sso += __shfl_xor(sso, m, 64);
    }
    __shared__ float rx[4], ro[4];
    const int wid = tid >> 6;
    if ((tid & 63) == 0) { rx[wid] = ssx; ro[wid] = sso; }
    __syncthreads();
    float tsx = rx[0] + rx[1] + rx[2] + rx[3];
    float tso = ro[0] + ro[1] + ro[2] + ro[3];
    float scale = sqrtf(tsx) / (sqrtf(tso) + 1e-8f) * en[0];
    ov.x *= scale; ov.y *= scale; ov.z *= scale; ov.w *= scale;
    *(float4*)&orow[tid * 4] = ov;
}

// ------------------------------------------------------------- launch
extern "C" void kernel_launch(void* const* d_in, const int* in_sizes, int n_in,
                              void* d_out, int out_size, void* d_ws, size_t ws_size,
                              hipStream_t stream)
{
    const float* x     = (const float*)d_in[0];
    const float* fd    = (const float*)d_in[1];
    const float* wq    = (const float*)d_in[2];
    const float* bq    = (const float*)d_in[3];
    const float* wk    = (const float*)d_in[4];
    const float* bk    = (const float*)d_in[5];
    const float* wv    = (const float*)d_in[6];
    const float* bv    = (const float*)d_in[7];
    const float* wo    = (const float*)d_in[8];
    const float* bo    = (const float*)d_in[9];
    const float* alpha = (const float*)d_in[10];
    const float* fas   = (const float*)d_in[11];
    const float* en    = (const float*)d_in[12];
    float* out = (float*)d_out;
    float* ws  = (float*)d_ws;

    float* qT  = ws;                               // -> qpk -> wopk
    float* kT  = ws + (size_t)1 * 4194304;         // -> kpk
    float* vT  = ws + (size_t)2 * 4194304;         // -> vpk
    float* qiT = ws + (size_t)3 * 4194304;         // wqkv-pk -> qipk
    float* kiT = ws + (size_t)4 * 4194304;         // -> kipk
    float* att = ws + (size_t)5 * 4194304;         // xpk -> attpk
    float2* tw   = (float2*)(ws + (size_t)6 * 4194304);
    float2* filt = (float2*)(ws + (size_t)6 * 4194304 + 2048);

    unsigned* wqkvpk = (unsigned*)qiT;
    unsigned* xpk    = (unsigned*)att;
    unsigned* attpk  = (unsigned*)att;
    unsigned* wopk   = (unsigned*)qT;

    k_init_tables<<<8, 256, 0, stream>>>(tw, filt, fd, alpha, fas);
    k_prep_w<<<dim3(16, 16), 256, 0, stream>>>(wq, wqkvpk);
    k_prep_w<<<dim3(16, 16), 256, 0, stream>>>(wk, wqkvpk + 1048576);
    k_prep_w<<<dim3(16, 16), 256, 0, stream>>>(wv, wqkvpk + 2097152);
    k_prep_x<<<1024, 256, 0, stream>>>(x, xpk);
    k_gemm_qkv<<<dim3(8, 32, 3), 256, 0, stream>>>(xpk, wqkvpk, bq, bk, bv,
                                                   qT, kT, vT);
    k_fft_filter<<<6144, 256, 0, stream>>>(qT, kT, vT, qiT, kiT, tw, filt);
    k_flash<<<512, 512, 0, stream>>>((const unsigned*)qT, (const unsigned*)qiT,
                                     (const unsigned*)kT, (const unsigned*)kiT,
                                     (const unsigned*)vT, attpk);
    k_prep_w<<<dim3(16, 16), 256, 0, stream>>>(wo, wopk);
    k_gemm_out<<<dim3(32, 8), 256, 0, stream>>>(attpk, wopk, bo, out);
    k_norm<<<4096, 256, 0, stream>>>(x, out, en);
}

// Round 6
// 575.793 us; speedup vs baseline: 1.1578x; 1.1578x over previous
//
#include <hip/hip_runtime.h>
#include <math.h>

// SpectralAttention gfx950 — round 6: R4 base (2-barrier, single-buffer) with
// flash s-step widened 32->64 (halves barrier count, doubles per-phase compute
// for wave-level latency cover) + vectorized V staging (R5's verified win).
// B=2, T=2048, C=1024, H=16, HD=64.
//
// Packed split format (u32): lo16 = fp16(v) ["hi" part], hi16 = fp16((v-hi)*2048).
// v = hi + lo/2048 to ~2^-22 rel.  3-term MFMA: D = Ah*Bh + (Ah*Bl + Al*Bh)/2048.
//
// ws layout (floats) with region reuse:
//   [0,  4M)  qT -> qpk -> wopk     [4M, 8M)  kT -> kpk    [8M, 12M) vT -> vpk
//   [12M,16M) wqkv-pk -> qipk      [16M,20M) kipk
//   [20M,24M) xpk -> attpk         24M: tables
// total 96 MB + 16 KB

typedef _Float16 half8 __attribute__((ext_vector_type(8)));
typedef float f32x4 __attribute__((ext_vector_type(4)));
#define MFMA16 __builtin_amdgcn_mfma_f32_16x16x32_f16

__device__ inline unsigned pack_split(float v) {
    _Float16 h = (_Float16)v;
    float r = (v - (float)h) * 2048.0f;
    _Float16 l = (_Float16)r;
    union { _Float16 f; unsigned short u; } a, b;
    a.f = h; b.f = l;
    return (unsigned)a.u | ((unsigned)b.u << 16);
}
__device__ inline _Float16 lo16(unsigned u) {
    union { unsigned short s; _Float16 f; } x; x.s = (unsigned short)(u & 0xffffu); return x.f;
}
__device__ inline _Float16 hi16(unsigned u) {
    union { unsigned short s; _Float16 f; } x; x.s = (unsigned short)(u >> 16); return x.f;
}

// split 8 packed u32 into hi-half8 / lo-half8 via byte-perms, store as 2 b128
__device__ inline void write_split(_Float16* dh, _Float16* dl, uint4 u0, uint4 u1) {
    uint4 lo, hi;
    lo.x = __builtin_amdgcn_perm(u0.y, u0.x, 0x05040100u);
    lo.y = __builtin_amdgcn_perm(u0.w, u0.z, 0x05040100u);
    lo.z = __builtin_amdgcn_perm(u1.y, u1.x, 0x05040100u);
    lo.w = __builtin_amdgcn_perm(u1.w, u1.z, 0x05040100u);
    hi.x = __builtin_amdgcn_perm(u0.y, u0.x, 0x07060302u);
    hi.y = __builtin_amdgcn_perm(u0.w, u0.z, 0x07060302u);
    hi.z = __builtin_amdgcn_perm(u1.y, u1.x, 0x07060302u);
    hi.w = __builtin_amdgcn_perm(u1.w, u1.z, 0x07060302u);
    *(uint4*)dh = lo;
    *(uint4*)dl = hi;
}

// ---------------------------------------------------------------- init tables
__global__ __launch_bounds__(256) void k_init_tables(
    float2* __restrict__ tw, float2* __restrict__ filt,
    const float* __restrict__ fd, const float* __restrict__ alpha,
    const float* __restrict__ fas)
{
    int i = blockIdx.x * 256 + threadIdx.x;
    double aa = (double)alpha[0] + (double)fas[0] * ((double)fd[0] - 1.5);
    if (i < 1024) {
        double ang = -2.0 * 3.14159265358979323846 * (double)i / 2048.0;
        double s, c;
        sincos(ang, &s, &c);
        tw[i] = make_float2((float)c, (float)s);
    }
    if (i < 2048) {
        double fr = (i < 1024) ? (double)i / 2048.0 : ((double)i - 2048.0) / 2048.0;
        double ph = aa * atan(log(fabs(fr) + 1e-10));
        double s, c;
        sincos(ph, &s, &c);
        filt[i] = make_float2((float)c, (float)s);
    }
}

// ------------------------------------------------------- prep: W^T pack-split
__global__ __launch_bounds__(256) void k_prep_w(
    const float* __restrict__ W, unsigned* __restrict__ Wpk)
{
    __shared__ float tile[64][65];
    const int kb = blockIdx.x * 64, cb = blockIdx.y * 64;
    const int t = threadIdx.x, r = t >> 4, c4 = (t & 15) * 4;
#pragma unroll
    for (int i = 0; i < 4; ++i) {
        int row = r + 16 * i;
        float4 v = *(const float4*)&W[(size_t)(kb + row) * 1024 + cb + c4];
        tile[row][c4 + 0] = v.x; tile[row][c4 + 1] = v.y;
        tile[row][c4 + 2] = v.z; tile[row][c4 + 3] = v.w;
    }
    __syncthreads();
#pragma unroll
    for (int i = 0; i < 4; ++i) {
        int crow = r + 16 * i;
        uint4 o;
        o.x = pack_split(tile[c4 + 0][crow]);
        o.y = pack_split(tile[c4 + 1][crow]);
        o.z = pack_split(tile[c4 + 2][crow]);
        o.w = pack_split(tile[c4 + 3][crow]);
        *(uint4*)&Wpk[(size_t)(cb + crow) * 1024 + kb + c4] = o;
    }
}

// ------------------------------------------------------- prep: x pack-split
__global__ __launch_bounds__(256) void k_prep_x(
    const float* __restrict__ x, unsigned* __restrict__ xpk)
{
    const int base = blockIdx.x * 4096 + threadIdx.x * 4;
#pragma unroll
    for (int i = 0; i < 4; ++i) {
        int idx = base + i * 1024;
        float4 v = *(const float4*)&x[idx];
        uint4 o;
        o.x = pack_split(v.x); o.y = pack_split(v.y);
        o.z = pack_split(v.z); o.w = pack_split(v.w);
        *(uint4*)&xpk[idx] = o;
    }
}

// --------------------------------------------------- QKV GEMM (MFMA f16-split)
// out^T[c][t] = W^T X^T. 128x128 tile, single-buffer, 2 barriers/K-step (R4).
__global__ __launch_bounds__(256) void k_gemm_qkv(
    const unsigned* __restrict__ xpk, const unsigned* __restrict__ wpk,
    const float* __restrict__ bq, const float* __restrict__ bk,
    const float* __restrict__ bv,
    float* __restrict__ qT, float* __restrict__ kT, float* __restrict__ vT)
{
    __shared__ __align__(16) _Float16 Ab[8][2][64][8];   // 16 KB
    __shared__ __align__(16) _Float16 Bb[8][2][64][8];   // 16 KB
    const int tid = threadIdx.x;
    const int mat = blockIdx.z;
    const unsigned* Apk = wpk + (size_t)mat * 1048576;
    const float* bias = (mat == 0) ? bq : (mat == 1) ? bk : bv;
    float* outp       = (mat == 0) ? qT : (mat == 1) ? kT : vT;
    const int m0 = blockIdx.x * 128, n0 = blockIdx.y * 128;
    const int w = tid >> 6, lane = tid & 63, quad = lane >> 4, l15 = lane & 15;
    const int wm = (w & 1) * 4, wn = (w >> 1) * 4;

    const int chA = tid & 3, rA = tid >> 2;
    const int flA = (rA & 15) + 16 * chA, mtA = rA >> 4;
    const unsigned* gA0 = &Apk[(size_t)(m0 + rA) * 1024 + chA * 8];
    const unsigned* gA1 = gA0 + (size_t)64 * 1024;
    const unsigned* gB0 = &xpk[(size_t)(n0 + rA) * 1024 + chA * 8];
    const unsigned* gB1 = gB0 + (size_t)64 * 1024;

    uint4 pa0 = *(const uint4*)gA0, pa1 = *(const uint4*)(gA0 + 4);
    uint4 pa2 = *(const uint4*)gA1, pa3 = *(const uint4*)(gA1 + 4);
    uint4 pb0 = *(const uint4*)gB0, pb1 = *(const uint4*)(gB0 + 4);
    uint4 pb2 = *(const uint4*)gB1, pb3 = *(const uint4*)(gB1 + 4);

    f32x4 acc1[4][4], acc2[4][4];
    const f32x4 z4 = {0.f, 0.f, 0.f, 0.f};
#pragma unroll
    for (int i = 0; i < 4; ++i)
#pragma unroll
        for (int j = 0; j < 4; ++j) { acc1[i][j] = z4; acc2[i][j] = z4; }

    for (int k0 = 0; k0 < 1024; k0 += 32) {
        __syncthreads();
        write_split(&Ab[mtA][0][flA][0],     &Ab[mtA][1][flA][0],     pa0, pa1);
        write_split(&Ab[mtA + 4][0][flA][0], &Ab[mtA + 4][1][flA][0], pa2, pa3);
        write_split(&Bb[mtA][0][flA][0],     &Bb[mtA][1][flA][0],     pb0, pb1);
        write_split(&Bb[mtA + 4][0][flA][0], &Bb[mtA + 4][1][flA][0], pb2, pb3);
        __syncthreads();
        if (k0 < 992) {
            int kn = k0 + 32;
            pa0 = *(const uint4*)(gA0 + kn); pa1 = *(const uint4*)(gA0 + kn + 4);
            pa2 = *(const uint4*)(gA1 + kn); pa3 = *(const uint4*)(gA1 + kn + 4);
            pb0 = *(const uint4*)(gB0 + kn); pb1 = *(const uint4*)(gB0 + kn + 4);
            pb2 = *(const uint4*)(gB1 + kn); pb3 = *(const uint4*)(gB1 + kn + 4);
        }
        half8 ah[4], al[4];
#pragma unroll
        for (int mt = 0; mt < 4; ++mt) {
            ah[mt] = *(half8*)&Ab[wm + mt][0][lane][0];
            al[mt] = *(half8*)&Ab[wm + mt][1][lane][0];
        }
#pragma unroll
        for (int nt = 0; nt < 4; ++nt) {
            half8 bh = *(half8*)&Bb[wn + nt][0][lane][0];
            half8 bl = *(half8*)&Bb[wn + nt][1][lane][0];
#pragma unroll
            for (int mt = 0; mt < 4; ++mt) {
                acc1[mt][nt] = MFMA16(ah[mt], bh, acc1[mt][nt], 0, 0, 0);
                acc2[mt][nt] = MFMA16(ah[mt], bl, acc2[mt][nt], 0, 0, 0);
                acc2[mt][nt] = MFMA16(al[mt], bh, acc2[mt][nt], 0, 0, 0);
            }
        }
    }
    const int b_ = n0 >> 11, t0 = n0 & 2047;
#pragma unroll
    for (int mt = 0; mt < 4; ++mt) {
#pragma unroll
        for (int r_ = 0; r_ < 4; ++r_) {
            int m = m0 + (wm + mt) * 16 + quad * 4 + r_;
            float bs = bias[m];
            float* orow = &outp[(size_t)(b_ * 1024 + m) * 2048 + t0];
#pragma unroll
            for (int nt = 0; nt < 4; ++nt) {
                float val = acc1[mt][nt][r_] + acc2[mt][nt][r_] * (1.f / 2048.f) + bs;
                orow[(wn + nt) * 16 + l15] = val;
            }
        }
    }
}

// ------------------------------------------------------------- FFT + filter
__global__ __launch_bounds__(256) void k_fft_filter(
    float* __restrict__ qT, float* __restrict__ kT, float* __restrict__ vT,
    float* __restrict__ qiT, float* __restrict__ kiT,
    const float2* __restrict__ tw, const float2* __restrict__ filt)
{
    __shared__ float2 sf[2048];
    const int bid = blockIdx.x;          // 0..6143
    const int mat = bid >> 11;
    const int seq = bid & 2047;
    float* base = (mat == 0) ? qT : (mat == 1) ? kT : vT;
    float* src = base + (size_t)seq * 2048;
    const int tid = threadIdx.x;

    for (int i = tid; i < 2048; i += 256) {
        int j = (int)(__brev((unsigned)i) >> 21);
        sf[j] = make_float2(src[i], 0.f);
    }
    __syncthreads();
    for (int st = 1; st <= 11; ++st) {
        const int half = 1 << (st - 1);
        const int shift = 11 - st;
        for (int u = tid; u < 1024; u += 256) {
            int pos = u & (half - 1);
            int bi = 2 * u - pos;
            float2 w = tw[pos << shift];
            float2 a = sf[bi], b = sf[bi + half];
            float tr = w.x * b.x - w.y * b.y;
            float ti = w.x * b.y + w.y * b.x;
            sf[bi]        = make_float2(a.x + tr, a.y + ti);
            sf[bi + half] = make_float2(a.x - tr, a.y - ti);
        }
        __syncthreads();
    }
    unsigned* dst_re = (unsigned*)src;
    unsigned* dst_im = (mat == 0) ? (unsigned*)(qiT + (size_t)seq * 2048)
                                  : (unsigned*)(kiT + (size_t)seq * 2048);
    for (int i = tid; i < 2048; i += 256) {
        float2 z = sf[i];
        float2 f = filt[i];
        float re = z.x * f.x - z.y * f.y;
        float im = z.x * f.y + z.y * f.x;
        if (mat == 0) {
            dst_re[i] = pack_split(0.125f * re);
            dst_im[i] = pack_split(0.125f * im);
        } else if (mat == 1) {
            dst_re[i] = pack_split(re);
            dst_im[i] = pack_split(-im);
        } else {
            dst_re[i] = pack_split(re);
        }
    }
}

// ------------------------------------------------------------- flash (MFMA f16)
// 512 thr = 8 waves; block = (bh, t-tile 128); s-step 64; 2-barrier per iter.
// K staged fully coalesced (s across 64 lanes); V staged vectorized b128.
__global__ __launch_bounds__(512) void k_flash(
    const unsigned* __restrict__ qpk, const unsigned* __restrict__ qipk,
    const unsigned* __restrict__ kpk, const unsigned* __restrict__ kipk,
    const unsigned* __restrict__ vpk, unsigned* __restrict__ attpk)
{
    __shared__ __align__(16) _Float16 Kbuf[4][4][2][64][8];  // 32KB [st][kc][hl][lane][j]
    __shared__ __align__(16) _Float16 Vbuf[2][4][2][64][8];  // 16KB [sc2][nt][hl][lane][j]
    __shared__ __align__(16) _Float16 Pbuf[8][16][64];       // 16KB [w][m][s]

    const int tid = threadIdx.x;
    const int w = tid >> 6, lane = tid & 63;
    const int quad = lane >> 4, l15 = lane & 15;
    const int bh = blockIdx.x >> 4, tb = blockIdx.x & 15;
    const size_t bc = (size_t)bh * 64;
    const int tw0 = tb * 128 + w * 16;

    // Q A-frags in registers (loaded once)
    half8 aqh[4], aql[4];
#pragma unroll
    for (int kc = 0; kc < 4; ++kc) {
#pragma unroll
        for (int j = 0; j < 8; ++j) {
            int d = kc * 32 + quad * 8 + j;
            int t = tw0 + l15;
            unsigned u = (d < 64) ? qpk[(bc + d) * 2048 + t]
                                  : qipk[(bc + d - 64) * 2048 + t];
            aqh[kc][j] = lo16(u);
            aql[kc][j] = hi16(u);
        }
    }

    f32x4 O1[4], O2[4];
    const f32x4 zero4 = {0.f, 0.f, 0.f, 0.f};
#pragma unroll
    for (int nt = 0; nt < 4; ++nt) { O1[nt] = zero4; O2[nt] = zero4; }
    float m_[4] = {-3e38f, -3e38f, -3e38f, -3e38f};
    float l_[4] = {0.f, 0.f, 0.f, 0.f};

    // K staging: task0 -> real plane (d 0..63), task1 -> imag plane (d 64..127)
    const int sK = tid & 63;           // s within tile: coalesced across wave
    const int dc0 = tid >> 6;          // 0..7 -> d chunk dc0 (task0), dc0+8 (task1)
    const int stK = sK >> 4;
    const int kcK0 = dc0 >> 2;         // 0..1; task1 kc = kcK0+2
    const int laneK = (sK & 15) + ((dc0 & 3) << 4);
    const unsigned* kre = &kpk[(bc + dc0 * 8) * 2048 + sK];
    const unsigned* kim = &kipk[(bc + dc0 * 8) * 2048 + sK];
    // V staging (tid<256): 8 consecutive s at fixed d, B-frag row order
    const int ntV = tid >> 6, laneV = tid & 63;
    const int dV = ntV * 16 + (laneV & 15), sblk = (laneV >> 4) * 8;
    const unsigned* vbase = &vpk[(bc + dV) * 2048 + sblk];

    for (int it = 0; it < 32; ++it) {
        const int s0 = it * 64;
        __syncthreads();                     // prior compute reads done
        unsigned ka[8], kb2[8];
#pragma unroll
        for (int j = 0; j < 8; ++j) ka[j]  = kre[(size_t)j * 2048 + s0];
#pragma unroll
        for (int j = 0; j < 8; ++j) kb2[j] = kim[(size_t)j * 2048 + s0];
        uint4 va0, va1, vb0, vb1;
        if (tid < 256) {
            const unsigned* vp = vbase + s0;
            va0 = *(const uint4*)vp;        va1 = *(const uint4*)(vp + 4);
            vb0 = *(const uint4*)(vp + 32); vb1 = *(const uint4*)(vp + 36);
        }
        write_split(&Kbuf[stK][kcK0][0][laneK][0], &Kbuf[stK][kcK0][1][laneK][0],
                    *(uint4*)&ka[0], *(uint4*)&ka[4]);
        write_split(&Kbuf[stK][kcK0 + 2][0][laneK][0], &Kbuf[stK][kcK0 + 2][1][laneK][0],
                    *(uint4*)&kb2[0], *(uint4*)&kb2[4]);
        if (tid < 256) {
            write_split(&Vbuf[0][ntV][0][laneV][0], &Vbuf[0][ntV][1][laneV][0], va0, va1);
            write_split(&Vbuf[1][ntV][0][laneV][0], &Vbuf[1][ntV][1][laneV][0], vb0, vb1);
        }
        __syncthreads();

        // --- S = Q.K^T (3-term split): 48 MFMA
        f32x4 S1[4], S2[4];
#pragma unroll
        for (int st = 0; st < 4; ++st) { S1[st] = zero4; S2[st] = zero4; }
#pragma unroll
        for (int st = 0; st < 4; ++st) {
#pragma unroll
            for (int kc = 0; kc < 4; ++kc) {
                half8 bhf = *(half8*)&Kbuf[st][kc][0][lane][0];
                half8 blf = *(half8*)&Kbuf[st][kc][1][lane][0];
                S1[st] = MFMA16(aqh[kc], bhf, S1[st], 0, 0, 0);
                S2[st] = MFMA16(aqh[kc], blf, S2[st], 0, 0, 0);
                S2[st] = MFMA16(aql[kc], bhf, S2[st], 0, 0, 0);
            }
        }

        // --- online softmax (row t = quad*4+r; col s = st*16 + l15)
#pragma unroll
        for (int r = 0; r < 4; ++r) {
            float v0 = S1[0][r] + S2[0][r] * (1.f / 2048.f);
            float v1 = S1[1][r] + S2[1][r] * (1.f / 2048.f);
            float v2 = S1[2][r] + S2[2][r] * (1.f / 2048.f);
            float v3 = S1[3][r] + S2[3][r] * (1.f / 2048.f);
            float mt = fmaxf(fmaxf(v0, v1), fmaxf(v2, v3));
#pragma unroll
            for (int msk = 1; msk < 16; msk <<= 1)
                mt = fmaxf(mt, __shfl_xor(mt, msk, 16));
            float mn = fmaxf(m_[r], mt);
            float al = __expf(m_[r] - mn);
            m_[r] = mn;
            float p0 = __expf(v0 - mn);
            float p1 = __expf(v1 - mn);
            float p2 = __expf(v2 - mn);
            float p3 = __expf(v3 - mn);
            float rs = (p0 + p1) + (p2 + p3);
#pragma unroll
            for (int msk = 1; msk < 16; msk <<= 1)
                rs += __shfl_xor(rs, msk, 16);
            l_[r] = l_[r] * al + rs;
#pragma unroll
            for (int nt = 0; nt < 4; ++nt) { O1[nt][r] *= al; O2[nt][r] *= al; }
            int t = quad * 4 + r;
            Pbuf[w][t][l15]      = (_Float16)p0;
            Pbuf[w][t][l15 + 16] = (_Float16)p1;
            Pbuf[w][t][l15 + 32] = (_Float16)p2;
            Pbuf[w][t][l15 + 48] = (_Float16)p3;
        }
        // Pbuf is wave-private: no barrier needed

        // --- PV accumulate: 16 MFMA
#pragma unroll
        for (int sc2 = 0; sc2 < 2; ++sc2) {
            half8 ap = *(half8*)&Pbuf[w][l15][sc2 * 32 + quad * 8];
#pragma unroll
            for (int nt = 0; nt < 4; ++nt) {
                half8 vh = *(half8*)&Vbuf[sc2][nt][0][lane][0];
                half8 vl = *(half8*)&Vbuf[sc2][nt][1][lane][0];
                O1[nt] = MFMA16(ap, vh, O1[nt], 0, 0, 0);
                O2[nt] = MFMA16(ap, vl, O2[nt], 0, 0, 0);
            }
        }
    }

    const int b = bh >> 4, h = bh & 15;
#pragma unroll
    for (int r = 0; r < 4; ++r) {
        float inv = 1.0f / l_[r];
        int t = tw0 + quad * 4 + r;
        size_t row = (size_t)b * 2048 + t;
#pragma unroll
        for (int nt = 0; nt < 4; ++nt) {
            float val = (O1[nt][r] + O2[nt][r] * (1.f / 2048.f)) * inv;
            attpk[row * 1024 + h * 64 + nt * 16 + l15] = pack_split(val);
        }
    }
}

// --------------------------------------------------- out GEMM (MFMA f16-split)
__global__ __launch_bounds__(256) void k_gemm_out(
    const unsigned* __restrict__ attpk, const unsigned* __restrict__ wopk,
    const float* __restrict__ bo, float* __restrict__ out)
{
    __shared__ __align__(16) _Float16 Ab[8][2][64][8];
    __shared__ __align__(16) _Float16 Bb[8][2][64][8];
    const int tid = threadIdx.x;
    const int m0 = blockIdx.x * 128, n0 = blockIdx.y * 128;
    const int w = tid >> 6, lane = tid & 63, quad = lane >> 4, l15 = lane & 15;
    const int wm = (w & 1) * 4, wn = (w >> 1) * 4;

    const int chA = tid & 3, rA = tid >> 2;
    const int flA = (rA & 15) + 16 * chA, mtA = rA >> 4;
    const unsigned* gA0 = &attpk[(size_t)(m0 + rA) * 1024 + chA * 8];
    const unsigned* gA1 = gA0 + (size_t)64 * 1024;
    const unsigned* gB0 = &wopk[(size_t)(n0 + rA) * 1024 + chA * 8];
    const unsigned* gB1 = gB0 + (size_t)64 * 1024;

    uint4 pa0 = *(const uint4*)gA0, pa1 = *(const uint4*)(gA0 + 4);
    uint4 pa2 = *(const uint4*)gA1, pa3 = *(const uint4*)(gA1 + 4);
    uint4 pb0 = *(const uint4*)gB0, pb1 = *(const uint4*)(gB0 + 4);
    uint4 pb2 = *(const uint4*)gB1, pb3 = *(const uint4*)(gB1 + 4);

    f32x4 acc1[4][4], acc2[4][4];
    const f32x4 z4 = {0.f, 0.f, 0.f, 0.f};
#pragma unroll
    for (int i = 0; i < 4; ++i)
#pragma unroll
        for (int j = 0; j < 4; ++j) { acc1[i][j] = z4; acc2[i][j] = z4; }

    for (int k0 = 0; k0 < 1024; k0 += 32) {
        __syncthreads();
        write_split(&Ab[mtA][0][flA][0],     &Ab[mtA][1][flA][0],     pa0, pa1);
        write_split(&Ab[mtA + 4][0][flA][0], &Ab[mtA + 4][1][flA][0], pa2, pa3);
        write_split(&Bb[mtA][0][flA][0],     &Bb[mtA][1][flA][0],     pb0, pb1);
        write_split(&Bb[mtA + 4][0][flA][0], &Bb[mtA + 4][1][flA][0], pb2, pb3);
        __syncthreads();
        if (k0 < 992) {
            int kn = k0 + 32;
            pa0 = *(const uint4*)(gA0 + kn); pa1 = *(const uint4*)(gA0 + kn + 4);
            pa2 = *(const uint4*)(gA1 + kn); pa3 = *(const uint4*)(gA1 + kn + 4);
            pb0 = *(const uint4*)(gB0 + kn); pb1 = *(const uint4*)(gB0 + kn + 4);
            pb2 = *(const uint4*)(gB1 + kn); pb3 = *(const uint4*)(gB1 + kn + 4);
        }
        half8 ah[4], al[4];
#pragma unroll
        for (int mt = 0; mt < 4; ++mt) {
            ah[mt] = *(half8*)&Ab[wm + mt][0][lane][0];
            al[mt] = *(half8*)&Ab[wm + mt][1][lane][0];
        }
#pragma unroll
        for (int nt = 0; nt < 4; ++nt) {
            half8 bh = *(half8*)&Bb[wn + nt][0][lane][0];
            half8 bl = *(half8*)&Bb[wn + nt][1][lane][0];
#pragma unroll
            for (int mt = 0; mt < 4; ++mt) {
                acc1[mt][nt] = MFMA16(ah[mt], bh, acc1[mt][nt], 0, 0, 0);
                acc2[mt][nt] = MFMA16(ah[mt], bl, acc2[mt][nt], 0, 0, 0);
                acc2[mt][nt] = MFMA16(al[mt], bh, acc2[mt][nt], 0, 0, 0);
            }
        }
    }
#pragma unroll
    for (int mt = 0; mt < 4; ++mt) {
#pragma unroll
        for (int r_ = 0; r_ < 4; ++r_) {
            int m = m0 + (wm + mt) * 16 + quad * 4 + r_;
            float* orow = &out[(size_t)m * 1024 + n0];
#pragma unroll
            for (int nt = 0; nt < 4; ++nt) {
                int n = (wn + nt) * 16 + l15;
                float val = acc1[mt][nt][r_] + acc2[mt][nt][r_] * (1.f / 2048.f)
                          + bo[n0 + n];
                orow[n] = val;
            }
        }
    }
}

// ------------------------------------------------------------- energy renorm
__global__ __launch_bounds__(256) void k_norm(
    const float* __restrict__ x, float* __restrict__ out,
    const float* __restrict__ en)
{
    const int row = blockIdx.x;
    const int tid = threadIdx.x;
    const float* xr = x + (size_t)row * 1024;
    float* orow = out + (size_t)row * 1024;
    float4 xv = *(const float4*)&xr[tid * 4];
    float4 ov = *(const float4*)&orow[tid * 4];
    float ssx = xv.x * xv.x + xv.y * xv.y + xv.z * xv.z + xv.w * xv.w;
    float sso = ov.x * ov.x + ov.y * ov.y + ov.z * ov.z + ov.w * ov.w;
#pragma unroll
    for (int m = 1; m <= 32; m <<= 1) {
        ssx += __shfl_xor(ssx, m, 64);
        sso += __shfl_xor(sso, m, 64);
    }
    __shared__ float rx[4], ro[4];
    const int wid = tid >> 6;
    if ((tid & 63) == 0) { rx[wid] = ssx; ro[wid] = sso; }
    __syncthreads();
    float tsx = rx[0] + rx[1] + rx[2] + rx[3];
    float tso = ro[0] + ro[1] + ro[2] + ro[3];
    float scale = sqrtf(tsx) / (sqrtf(tso) + 1e-8f) * en[0];
    ov.x *= scale; ov.y *= scale; ov.z *= scale; ov.w *= scale;
    *(float4*)&orow[tid * 4] = ov;
}

// ------------------------------------------------------------- launch
extern "C" void kernel_launch(void* const* d_in, const int* in_sizes, int n_in,
                              void* d_out, int out_size, void* d_ws, size_t ws_size,
                              hipStream_t stream)
{
    const float* x     = (const float*)d_in[0];
    const float* fd    = (const float*)d_in[1];
    const float* wq    = (const float*)d_in[2];
    const float* bq    = (const float*)d_in[3];
    const float* wk    = (const float*)d_in[4];
    const float* bk    = (const float*)d_in[5];
    const float* wv    = (const float*)d_in[6];
    const float* bv    = (const float*)d_in[7];
    const float* wo    = (const float*)d_in[8];
    const float* bo    = (const float*)d_in[9];
    const float* alpha = (const float*)d_in[10];
    const float* fas   = (const float*)d_in[11];
    const float* en    = (const float*)d_in[12];
    float* out = (float*)d_out;
    float* ws  = (float*)d_ws;

    float* qT  = ws;                               // -> qpk -> wopk
    float* kT  = ws + (size_t)1 * 4194304;         // -> kpk
    float* vT  = ws + (size_t)2 * 4194304;         // -> vpk
    float* qiT = ws + (size_t)3 * 4194304;         // wqkv-pk -> qipk
    float* kiT = ws + (size_t)4 * 4194304;         // -> kipk
    float* att = ws + (size_t)5 * 4194304;         // xpk -> attpk
    float2* tw   = (float2*)(ws + (size_t)6 * 4194304);
    float2* filt = (float2*)(ws + (size_t)6 * 4194304 + 2048);

    unsigned* wqkvpk = (unsigned*)qiT;
    unsigned* xpk    = (unsigned*)att;
    unsigned* attpk  = (unsigned*)att;
    unsigned* wopk   = (unsigned*)qT;

    k_init_tables<<<8, 256, 0, stream>>>(tw, filt, fd, alpha, fas);
    k_prep_w<<<dim3(16, 16), 256, 0, stream>>>(wq, wqkvpk);
    k_prep_w<<<dim3(16, 16), 256, 0, stream>>>(wk, wqkvpk + 1048576);
    k_prep_w<<<dim3(16, 16), 256, 0, stream>>>(wv, wqkvpk + 2097152);
    k_prep_x<<<1024, 256, 0, stream>>>(x, xpk);
    k_gemm_qkv<<<dim3(8, 32, 3), 256, 0, stream>>>(xpk, wqkvpk, bq, bk, bv,
                                                   qT, kT, vT);
    k_fft_filter<<<6144, 256, 0, stream>>>(qT, kT, vT, qiT, kiT, tw, filt);
    k_flash<<<512, 512, 0, stream>>>((const unsigned*)qT, (const unsigned*)qiT,
                                     (const unsigned*)kT, (const unsigned*)kiT,
                                     (const unsigned*)vT, attpk);
    k_prep_w<<<dim3(16, 16), 256, 0, stream>>>(wo, wopk);
    k_gemm_out<<<dim3(32, 8), 256, 0, stream>>>(attpk, wopk, bo, out);
    k_norm<<<4096, 256, 0, stream>>>(x, out, en);
}